// Round 1
// baseline (572.034 us; speedup 1.0000x reference)
//
#include <hip/hip_runtime.h>

#define N_SRC 100000
#define N_DST 20000
#define NE    1250000
#define D     64
#define NEG_SLOPE 0.2f

// ---- float <-> ordered-uint encoding for atomicMax on floats ----
__device__ __forceinline__ unsigned enc_f32(float f) {
    unsigned u = __float_as_uint(f);
    return (u & 0x80000000u) ? ~u : (u | 0x80000000u);
}
__device__ __forceinline__ float dec_f32(unsigned u) {
    unsigned b = (u & 0x80000000u) ? (u ^ 0x80000000u) : ~u;
    return __uint_as_float(b);
}
// enc(-inf) = ~0xFF800000 = 0x007FFFFF
#define ENC_NEG_INF 0x007FFFFFu

// ---- K0: wad[k] = sum_c W[k][c] * att_dst[c]  (64 threads) ----
__global__ void k_wad(const float* __restrict__ W,
                      const float* __restrict__ att_dst,
                      float* __restrict__ wad) {
    int k = threadIdx.x;  // 0..63
    float s = 0.f;
#pragma unroll
    for (int c = 0; c < D; ++c) s += W[k * D + c] * att_dst[c];
    wad[k] = s;
}

// ---- K1: h = x @ W, a_src = h @ att_src.  4 rows/block, wave per row ----
__global__ __launch_bounds__(256) void k_h(const float* __restrict__ x,
                                           const float* __restrict__ W,
                                           const float* __restrict__ att_src,
                                           float* __restrict__ h,
                                           float* __restrict__ a_src) {
    __shared__ float Ws[D * D];
    __shared__ float xs[4][D];
    int tid = threadIdx.x;
    for (int i = tid; i < D * D; i += 256) Ws[i] = W[i];
    int ty = tid >> 6, c = tid & 63;
    int row = blockIdx.x * 4 + ty;   // N_SRC = 100000 = 4*25000, always valid
    xs[ty][c] = x[row * D + c];
    __syncthreads();
    float acc = 0.f;
#pragma unroll
    for (int k = 0; k < D; ++k) acc = fmaf(xs[ty][k], Ws[k * D + c], acc);
    h[row * D + c] = acc;
    float p = acc * att_src[c];
#pragma unroll
    for (int off = 32; off; off >>= 1) p += __shfl_xor(p, off, 64);
    if (c == 0) a_src[row] = p;
}

// ---- K2: a_dst[i] = dot(x[res_n_id[i]], wad).  wave per dst ----
__global__ __launch_bounds__(256) void k_adst(const float* __restrict__ x,
                                              const int* __restrict__ res_n_id,
                                              const float* __restrict__ wad,
                                              float* __restrict__ a_dst) {
    int tid = threadIdx.x;
    int wid = blockIdx.x * 4 + (tid >> 6);
    int lane = tid & 63;
    if (wid >= N_DST) return;
    int row = res_n_id[wid];
    float p = x[row * D + lane] * wad[lane];
#pragma unroll
    for (int off = 32; off; off >>= 1) p += __shfl_xor(p, off, 64);
    if (lane == 0) a_dst[wid] = p;
}

// ---- K3: init accumulators (harness poisons ws/out with 0xAA every call) ----
__global__ void k_init(float* __restrict__ out,
                       unsigned* __restrict__ m_int,
                       float* __restrict__ denom) {
    int i = blockIdx.x * blockDim.x + threadIdx.x;
    if (i < N_DST * D) out[i] = 0.f;
    if (i < N_DST) { m_int[i] = ENC_NEG_INF; denom[i] = 0.f; }
}

// ---- K4: per-edge score + segment max ----
__global__ void k_edge1(const int* __restrict__ es, const int* __restrict__ ed,
                        const float* __restrict__ a_src,
                        const float* __restrict__ a_dst,
                        float* __restrict__ e, unsigned* __restrict__ m_int) {
    int i = blockIdx.x * blockDim.x + threadIdx.x;
    if (i >= NE) return;
    float v = a_src[es[i]] + a_dst[ed[i]];
    v = v > 0.f ? v : NEG_SLOPE * v;
    e[i] = v;
    atomicMax(&m_int[ed[i]], enc_f32(v));
}

// ---- K5: fused exp + denom + weighted scatter.  wave per edge ----
__global__ __launch_bounds__(256) void k_edge2(const int* __restrict__ es,
                                               const int* __restrict__ ed,
                                               const float* __restrict__ e,
                                               const unsigned* __restrict__ m_int,
                                               const float* __restrict__ h,
                                               float* __restrict__ denom,
                                               float* __restrict__ out) {
    int tid = threadIdx.x;
    int eidx = blockIdx.x * 4 + (tid >> 6);
    int lane = tid & 63;
    if (eidx >= NE) return;
    int s = es[eidx], d = ed[eidx];
    float m = dec_f32(m_int[d]);
    float ex = __expf(e[eidx] - m);
    if (lane == 0) atomicAdd(&denom[d], ex);
    atomicAdd(&out[d * D + lane], h[s * D + lane] * ex);
}

// ---- K6: normalize + bias ----
__global__ void k_final(float* __restrict__ out,
                        const float* __restrict__ denom,
                        const float* __restrict__ bias) {
    int i = blockIdx.x * blockDim.x + threadIdx.x;
    if (i >= N_DST * D) return;
    out[i] = out[i] / (denom[i >> 6] + 1e-16f) + bias[i & 63];
}

extern "C" void kernel_launch(void* const* d_in, const int* in_sizes, int n_in,
                              void* d_out, int out_size, void* d_ws, size_t ws_size,
                              hipStream_t stream) {
    const float* x        = (const float*)d_in[0];
    const int*   res_n_id = (const int*)d_in[1];
    const int*   edge_src = (const int*)d_in[2];
    const int*   edge_dst = (const int*)d_in[3];
    const float* W        = (const float*)d_in[4];
    const float* att_src  = (const float*)d_in[5];
    const float* att_dst  = (const float*)d_in[6];
    const float* bias     = (const float*)d_in[7];
    float* out = (float*)d_out;

    char* w = (char*)d_ws;
    float*    h     = (float*)w;    w += (size_t)N_SRC * D * 4;   // 25.6 MB
    float*    a_src = (float*)w;    w += (size_t)N_SRC * 4;       // 400 KB
    float*    a_dst = (float*)w;    w += (size_t)N_DST * 4;       // 80 KB
    float*    wad   = (float*)w;    w += 256;
    float*    e     = (float*)w;    w += (size_t)NE * 4;          // 5 MB
    unsigned* m_int = (unsigned*)w; w += (size_t)N_DST * 4;
    float*    denom = (float*)w;    w += (size_t)N_DST * 4;

    k_wad<<<1, 64, 0, stream>>>(W, att_dst, wad);
    k_h<<<N_SRC / 4, 256, 0, stream>>>(x, W, att_src, h, a_src);
    k_adst<<<(N_DST + 3) / 4, 256, 0, stream>>>(x, res_n_id, wad, a_dst);
    k_init<<<(N_DST * D + 255) / 256, 256, 0, stream>>>(out, m_int, denom);
    k_edge1<<<(NE + 255) / 256, 256, 0, stream>>>(edge_src, edge_dst, a_src, a_dst, e, m_int);
    k_edge2<<<(NE + 3) / 4, 256, 0, stream>>>(edge_src, edge_dst, e, m_int, h, denom, out);
    k_final<<<(N_DST * D + 255) / 256, 256, 0, stream>>>(out, denom, bias);
}

// Round 2
// 372.491 us; speedup vs baseline: 1.5357x; 1.5357x over previous
//
#include <hip/hip_runtime.h>

#define N_SRC 100000
#define N_DST 20000
#define NE    1250000
#define D     64
#define NEG_SLOPE 0.2f

// ---- K0: wad[k] = sum_c W[k][c] * att_dst[c]  (64 threads) ----
__global__ void k_wad(const float* __restrict__ W,
                      const float* __restrict__ att_dst,
                      float* __restrict__ wad) {
    int k = threadIdx.x;  // 0..63
    float s = 0.f;
#pragma unroll
    for (int c = 0; c < D; ++c) s += W[k * D + c] * att_dst[c];
    wad[k] = s;
}

// ---- K1: h = x @ W, a_src = h @ att_src.  4 rows/block, wave per row ----
__global__ __launch_bounds__(256) void k_h(const float* __restrict__ x,
                                           const float* __restrict__ W,
                                           const float* __restrict__ att_src,
                                           float* __restrict__ h,
                                           float* __restrict__ a_src) {
    __shared__ float Ws[D * D];
    __shared__ float xs[4][D];
    int tid = threadIdx.x;
    for (int i = tid; i < D * D; i += 256) Ws[i] = W[i];
    int ty = tid >> 6, c = tid & 63;
    int row = blockIdx.x * 4 + ty;   // N_SRC = 100000 = 4*25000, always valid
    xs[ty][c] = x[row * D + c];
    __syncthreads();
    float acc = 0.f;
#pragma unroll
    for (int k = 0; k < D; ++k) acc = fmaf(xs[ty][k], Ws[k * D + c], acc);
    h[row * D + c] = acc;
    float p = acc * att_src[c];
#pragma unroll
    for (int off = 32; off; off >>= 1) p += __shfl_xor(p, off, 64);
    if (c == 0) a_src[row] = p;
}

// ---- K2: a_dst[i] = dot(x[res_n_id[i]], wad).  wave per dst ----
__global__ __launch_bounds__(256) void k_adst(const float* __restrict__ x,
                                              const int* __restrict__ res_n_id,
                                              const float* __restrict__ wad,
                                              float* __restrict__ a_dst) {
    int tid = threadIdx.x;
    int wid = blockIdx.x * 4 + (tid >> 6);
    int lane = tid & 63;
    if (wid >= N_DST) return;
    int row = res_n_id[wid];
    float p = x[row * D + lane] * wad[lane];
#pragma unroll
    for (int off = 32; off; off >>= 1) p += __shfl_xor(p, off, 64);
    if (lane == 0) a_dst[wid] = p;
}

// ---- K3: zero the histogram (ws is poisoned 0xAA every call) ----
__global__ void k_zero(int* __restrict__ hist) {
    int i = blockIdx.x * blockDim.x + threadIdx.x;
    if (i < N_DST) hist[i] = 0;
}

// ---- K4: histogram of edge_dst ----
__global__ void k_hist(const int* __restrict__ ed, int* __restrict__ hist) {
    int i = blockIdx.x * blockDim.x + threadIdx.x;
    if (i < NE) atomicAdd(&hist[ed[i]], 1);
}

// ---- K5: exclusive scan of hist -> offsets[N_DST+1], cursor copy (1 block) ----
__global__ __launch_bounds__(256) void k_scan(const int* __restrict__ hist,
                                              int* __restrict__ offsets,
                                              int* __restrict__ cursor) {
    __shared__ int part[256];
    const int CH = (N_DST + 255) / 256;  // 79
    int tid = threadIdx.x;
    int base = tid * CH;
    int s = 0;
    for (int j = 0; j < CH; ++j) {
        int i = base + j;
        if (i < N_DST) s += hist[i];
    }
    part[tid] = s;
    __syncthreads();
    for (int off = 1; off < 256; off <<= 1) {
        int v = (tid >= off) ? part[tid - off] : 0;
        __syncthreads();
        part[tid] += v;
        __syncthreads();
    }
    int run = (tid == 0) ? 0 : part[tid - 1];
    for (int j = 0; j < CH; ++j) {
        int i = base + j;
        if (i < N_DST) {
            offsets[i] = run;
            cursor[i]  = run;
            run += hist[i];
        }
    }
    if (tid == 0) offsets[N_DST] = part[255];
}

// ---- K6: scatter edges into dst-sorted order as packed {src, score} ----
__global__ void k_scatter(const int* __restrict__ es, const int* __restrict__ ed,
                          const float* __restrict__ a_src,
                          const float* __restrict__ a_dst,
                          int* __restrict__ cursor,
                          int2* __restrict__ packed) {
    int i = blockIdx.x * blockDim.x + threadIdx.x;
    if (i >= NE) return;
    int s = es[i], d = ed[i];
    float v = a_src[s] + a_dst[d];
    v = v > 0.f ? v : NEG_SLOPE * v;
    int pos = atomicAdd(&cursor[d], 1);
    packed[pos] = make_int2(s, __float_as_int(v));
}

// ---- K7: per-dst softmax-aggregate. wave per dst, lane = channel ----
__global__ __launch_bounds__(256) void k_agg(const int2* __restrict__ packed,
                                             const int* __restrict__ offsets,
                                             const float* __restrict__ h,
                                             const float* __restrict__ bias,
                                             float* __restrict__ out) {
    int tid = threadIdx.x;
    int wid = blockIdx.x * 4 + (tid >> 6);
    int lane = tid & 63;
    if (wid >= N_DST) return;
    int beg = offsets[wid], end = offsets[wid + 1];
    float b = bias[lane];
    if (beg == end) { out[wid * D + lane] = b; return; }

    // segment max (lanes stride the edge list, then shuffle-reduce)
    float mx = -1e30f;
    for (int j = beg + lane; j < end; j += 64)
        mx = fmaxf(mx, __int_as_float(packed[j].y));
#pragma unroll
    for (int off = 32; off; off >>= 1) mx = fmaxf(mx, __shfl_xor(mx, off, 64));

    // weighted accumulate (broadcast edge record, coalesced 256B h gather)
    float acc = 0.f, den = 0.f;
    int j = beg;
    for (; j + 3 < end; j += 4) {
        int2 p0 = packed[j], p1 = packed[j + 1], p2 = packed[j + 2], p3 = packed[j + 3];
        float w0 = __expf(__int_as_float(p0.y) - mx);
        float w1 = __expf(__int_as_float(p1.y) - mx);
        float w2 = __expf(__int_as_float(p2.y) - mx);
        float w3 = __expf(__int_as_float(p3.y) - mx);
        float h0 = h[p0.x * D + lane];
        float h1 = h[p1.x * D + lane];
        float h2 = h[p2.x * D + lane];
        float h3 = h[p3.x * D + lane];
        acc = fmaf(w0, h0, acc); acc = fmaf(w1, h1, acc);
        acc = fmaf(w2, h2, acc); acc = fmaf(w3, h3, acc);
        den += (w0 + w1) + (w2 + w3);
    }
    for (; j < end; ++j) {
        int2 p = packed[j];
        float wgt = __expf(__int_as_float(p.y) - mx);
        acc = fmaf(wgt, h[p.x * D + lane], acc);
        den += wgt;
    }
    out[wid * D + lane] = acc / (den + 1e-16f) + b;
}

extern "C" void kernel_launch(void* const* d_in, const int* in_sizes, int n_in,
                              void* d_out, int out_size, void* d_ws, size_t ws_size,
                              hipStream_t stream) {
    const float* x        = (const float*)d_in[0];
    const int*   res_n_id = (const int*)d_in[1];
    const int*   edge_src = (const int*)d_in[2];
    const int*   edge_dst = (const int*)d_in[3];
    const float* W        = (const float*)d_in[4];
    const float* att_src  = (const float*)d_in[5];
    const float* att_dst  = (const float*)d_in[6];
    const float* bias     = (const float*)d_in[7];
    float* out = (float*)d_out;

    char* w = (char*)d_ws;
    float* h       = (float*)w; w += (size_t)N_SRC * D * 4;     // 25.6 MB
    int2*  packed  = (int2*)w;  w += (size_t)NE * 8;            // 10 MB
    float* a_src   = (float*)w; w += (size_t)N_SRC * 4;         // 400 KB
    float* a_dst   = (float*)w; w += (size_t)N_DST * 4;         // 80 KB
    float* wad     = (float*)w; w += 256;
    int*   hist    = (int*)w;   w += (size_t)N_DST * 4;         // 80 KB
    int*   offsets = (int*)w;   w += (size_t)(N_DST + 1) * 4;
    int*   cursor  = (int*)w;   w += (size_t)N_DST * 4;

    k_wad<<<1, 64, 0, stream>>>(W, att_dst, wad);
    k_h<<<N_SRC / 4, 256, 0, stream>>>(x, W, att_src, h, a_src);
    k_adst<<<(N_DST + 3) / 4, 256, 0, stream>>>(x, res_n_id, wad, a_dst);
    k_zero<<<(N_DST + 255) / 256, 256, 0, stream>>>(hist);
    k_hist<<<(NE + 255) / 256, 256, 0, stream>>>(edge_dst, hist);
    k_scan<<<1, 256, 0, stream>>>(hist, offsets, cursor);
    k_scatter<<<(NE + 255) / 256, 256, 0, stream>>>(edge_src, edge_dst, a_src, a_dst, cursor, packed);
    k_agg<<<(N_DST + 3) / 4, 256, 0, stream>>>(packed, offsets, h, bias, out);
}